// Round 1
// baseline (1027.281 us; speedup 1.0000x reference)
//
#include <hip/hip_runtime.h>
#include <hip/hip_bf16.h>
#include <math.h>

#define NN 50000
#define NE 500000
#define DIN 264
#define HID 128
#define EDIM 16

// ---------------- CSR build (dst -> in-edges) ----------------
__global__ void k_count(const int* __restrict__ dst, int* __restrict__ cnt) {
    int e = blockIdx.x * blockDim.x + threadIdx.x;
    if (e < NE) atomicAdd(&cnt[dst[e]], 1);
}

__global__ void k_scan(const int* __restrict__ cnt, int* __restrict__ off) {
    __shared__ int buf[1024];
    __shared__ int carry_s;
    if (threadIdx.x == 0) carry_s = 0;
    __syncthreads();
    for (int base = 0; base < NN; base += 1024) {
        int i = base + threadIdx.x;
        int v = (i < NN) ? cnt[i] : 0;
        buf[threadIdx.x] = v;
        __syncthreads();
        for (int s = 1; s < 1024; s <<= 1) {
            int t = (threadIdx.x >= s) ? buf[threadIdx.x - s] : 0;
            __syncthreads();
            buf[threadIdx.x] += t;
            __syncthreads();
        }
        int incl = buf[threadIdx.x] + carry_s;
        if (i < NN) off[i + 1] = incl;
        __syncthreads();
        if (threadIdx.x == 1023) carry_s = incl;
        __syncthreads();
    }
    if (threadIdx.x == 0) off[0] = 0;
}

__global__ void k_copyoff(const int* __restrict__ off, int* __restrict__ cur) {
    int i = blockIdx.x * blockDim.x + threadIdx.x;
    if (i < NN) cur[i] = off[i];
}

__global__ void k_scatter(const int* __restrict__ src, const int* __restrict__ dst,
                          int* __restrict__ cur, int* __restrict__ csr_src,
                          int* __restrict__ csr_eid) {
    int e = blockIdx.x * blockDim.x + threadIdx.x;
    if (e < NE) {
        int p = atomicAdd(&cur[dst[e]], 1);
        csr_src[p] = src[e];
        csr_eid[p] = e;
    }
}

// ---------------- generic fp32 GEMM: C[Mx128] = A[MxK] @ B[Kx128] + bias ----------------
// tile 64(M) x 128(N), KT=8, 256 threads, each thread 8x4 outputs
__global__ __launch_bounds__(256) void k_gemm128(const float* __restrict__ A,
                                                 const float* __restrict__ B,
                                                 const float* __restrict__ bias,
                                                 float* __restrict__ C, int M, int K) {
    __shared__ float As[8][64];
    __shared__ float Bs[8][128];
    int t = threadIdx.x;
    int tx = t & 31, ty = t >> 5;
    int row0 = blockIdx.x * 64;
    float acc[8][4];
#pragma unroll
    for (int r = 0; r < 8; ++r)
#pragma unroll
        for (int c = 0; c < 4; ++c) acc[r][c] = 0.f;

    for (int k0 = 0; k0 < K; k0 += 8) {
        {   // A tile: 64x8, float2 per thread
            int m = t >> 2;
            int kk = (t & 3) * 2;
            int row = row0 + m;
            float2 v = make_float2(0.f, 0.f);
            if (row < M) v = *reinterpret_cast<const float2*>(&A[(size_t)row * K + k0 + kk]);
            As[kk][m] = v.x;
            As[kk + 1][m] = v.y;
        }
        {   // B tile: 8x128, float4 per thread (coalesced)
            int kk = t >> 5;
            int c = (t & 31) * 4;
            float4 v = *reinterpret_cast<const float4*>(&B[(size_t)(k0 + kk) * 128 + c]);
            *reinterpret_cast<float4*>(&Bs[kk][c]) = v;
        }
        __syncthreads();
#pragma unroll
        for (int kk = 0; kk < 8; ++kk) {
            float a[8], b[4];
#pragma unroll
            for (int r = 0; r < 8; ++r) a[r] = As[kk][ty * 8 + r];
#pragma unroll
            for (int c = 0; c < 4; ++c) b[c] = Bs[kk][tx * 4 + c];
#pragma unroll
            for (int r = 0; r < 8; ++r)
#pragma unroll
                for (int c = 0; c < 4; ++c) acc[r][c] += a[r] * b[c];
        }
        __syncthreads();
    }
    float4 bv = *reinterpret_cast<const float4*>(&bias[tx * 4]);
#pragma unroll
    for (int r = 0; r < 8; ++r) {
        int row = row0 + ty * 8 + r;
        if (row < M) {
            float4 o = make_float4(acc[r][0] + bv.x, acc[r][1] + bv.y,
                                   acc[r][2] + bv.z, acc[r][3] + bv.w);
            *reinterpret_cast<float4*>(&C[(size_t)row * 128 + tx * 4]) = o;
        }
    }
}

// ---------------- edge scoring: one thread per (edge, head) ----------------
// score[e,h] = sum_c leaky(xl[src][h,c] + xr[dst][h,c] + (ea @ We)[h,c]) * att[h,c]
__global__ __launch_bounds__(256) void k_edge_score(const float* __restrict__ xl,
                                                    const float* __restrict__ xr,
                                                    const float* __restrict__ ea,
                                                    const float* __restrict__ We,
                                                    const float* __restrict__ att,
                                                    const int* __restrict__ src,
                                                    const int* __restrict__ dst,
                                                    float* __restrict__ score) {
    __shared__ float sWe[EDIM * 128];
    __shared__ float sAtt[128];
    for (int i = threadIdx.x; i < EDIM * 128; i += 256) sWe[i] = We[i];
    if (threadIdx.x < 128) sAtt[threadIdx.x] = att[threadIdx.x];
    __syncthreads();

    int gid = blockIdx.x * 256 + threadIdx.x;
    int e = gid >> 2, h = gid & 3;
    if (e >= NE) return;

    float eav[EDIM];
#pragma unroll
    for (int j = 0; j < EDIM / 4; ++j) {
        float4 v = *reinterpret_cast<const float4*>(&ea[(size_t)e * EDIM + j * 4]);
        eav[j * 4 + 0] = v.x; eav[j * 4 + 1] = v.y;
        eav[j * 4 + 2] = v.z; eav[j * 4 + 3] = v.w;
    }
    const float4* xl4 = reinterpret_cast<const float4*>(&xl[(size_t)src[e] * 128 + h * 32]);
    const float4* xr4 = reinterpret_cast<const float4*>(&xr[(size_t)dst[e] * 128 + h * 32]);
    float m[32];
#pragma unroll
    for (int j = 0; j < 8; ++j) {
        float4 a = xl4[j], b = xr4[j];
        m[j * 4 + 0] = a.x + b.x; m[j * 4 + 1] = a.y + b.y;
        m[j * 4 + 2] = a.z + b.z; m[j * 4 + 3] = a.w + b.w;
    }
    const float* wrow = &sWe[h * 32];
#pragma unroll
    for (int k = 0; k < EDIM; ++k) {
        float a = eav[k];
        const float* w = &wrow[k * 128];
#pragma unroll
        for (int c = 0; c < 32; ++c) m[c] += a * w[c];
    }
    float s = 0.f;
    const float* at = &sAtt[h * 32];
#pragma unroll
    for (int c = 0; c < 32; ++c) {
        float g = m[c] > 0.f ? m[c] : 0.2f * m[c];
        s += g * at[c];
    }
    score[(size_t)e * 4 + h] = s;
}

// ---------------- block helpers ----------------
__device__ __forceinline__ float block_sum128(float v, volatile float* red) {
#pragma unroll
    for (int o = 32; o > 0; o >>= 1) v += __shfl_down(v, o, 64);
    int w = threadIdx.x >> 6;
    __syncthreads();
    if ((threadIdx.x & 63) == 0) red[w] = v;
    __syncthreads();
    return red[0] + red[1];
}

// ---------------- per-node softmax + aggregate + bias + ELU + residual + LN ----------------
__global__ __launch_bounds__(128) void k_node_agg(const int* __restrict__ off,
                                                  const int* __restrict__ csr_src,
                                                  const int* __restrict__ csr_eid,
                                                  const float* __restrict__ score,
                                                  const float* __restrict__ xl,
                                                  const float* __restrict__ residual,
                                                  const float* __restrict__ bias,
                                                  const float* __restrict__ gamma,
                                                  const float* __restrict__ beta,
                                                  float* __restrict__ out) {
    __shared__ float red[2];
    int i = blockIdx.x;
    int t = threadIdx.x;
    int h = t >> 5;
    int b0 = off[i], b1 = off[i + 1];

    float mx = -INFINITY;
    for (int k = b0; k < b1; ++k)
        mx = fmaxf(mx, score[(size_t)csr_eid[k] * 4 + h]);

    float denom = 0.f, acc = 0.f;
    for (int k = b0; k < b1; ++k) {
        int e = csr_eid[k];
        int s = csr_src[k];
        float ex = __expf(score[(size_t)e * 4 + h] - mx);
        denom += ex;
        acc += ex * xl[(size_t)s * 128 + t];
    }
    float o = acc / (denom + 1e-16f) + bias[t];
    o = o > 0.f ? o : (__expf(o) - 1.f);           // ELU
    float v = o + residual[(size_t)i * 128 + t];   // + residual
    float mean = block_sum128(v, red) * (1.f / 128.f);
    float d = v - mean;
    float var = block_sum128(d * d, red) * (1.f / 128.f);
    out[(size_t)i * 128 + t] = d * rsqrtf(var + 1e-5f) * gamma[t] + beta[t];
}

// ---------------- plain LN over 128 ----------------
__global__ __launch_bounds__(128) void k_ln(const float* __restrict__ in,
                                            const float* __restrict__ gamma,
                                            const float* __restrict__ beta,
                                            float* __restrict__ out) {
    __shared__ float red[2];
    int i = blockIdx.x, t = threadIdx.x;
    float v = in[(size_t)i * 128 + t];
    float mean = block_sum128(v, red) * (1.f / 128.f);
    float d = v - mean;
    float var = block_sum128(d * d, red) * (1.f / 128.f);
    out[(size_t)i * 128 + t] = d * rsqrtf(var + 1e-5f) * gamma[t] + beta[t];
}

extern "C" void kernel_launch(void* const* d_in, const int* in_sizes, int n_in,
                              void* d_out, int out_size, void* d_ws, size_t ws_size,
                              hipStream_t stream) {
    (void)in_sizes; (void)n_in; (void)out_size; (void)ws_size;
    const float* x     = (const float*)d_in[0];
    const float* ea    = (const float*)d_in[1];
    const float* Wl1   = (const float*)d_in[2];
    const float* bl1   = (const float*)d_in[3];
    const float* Wr1   = (const float*)d_in[4];
    const float* br1   = (const float*)d_in[5];
    const float* We1   = (const float*)d_in[6];
    const float* att1  = (const float*)d_in[7];
    const float* bias1 = (const float*)d_in[8];
    const float* Wl2   = (const float*)d_in[9];
    const float* bl2   = (const float*)d_in[10];
    const float* Wr2   = (const float*)d_in[11];
    const float* br2   = (const float*)d_in[12];
    const float* We2   = (const float*)d_in[13];
    const float* att2  = (const float*)d_in[14];
    const float* bias2 = (const float*)d_in[15];
    const float* Wres  = (const float*)d_in[16];
    const float* bres  = (const float*)d_in[17];
    const float* Wout  = (const float*)d_in[18];
    const float* bout  = (const float*)d_in[19];
    const float* g1    = (const float*)d_in[20];
    const float* bn1   = (const float*)d_in[21];
    const float* g2    = (const float*)d_in[22];
    const float* bn2   = (const float*)d_in[23];
    const float* go    = (const float*)d_in[24];
    const float* bo    = (const float*)d_in[25];
    const int*   ei    = (const int*)d_in[26];
    const int* srcv = ei;
    const int* dstv = ei + NE;
    float* outp = (float*)d_out;

    char* p = (char*)d_ws;
    auto carve = [&](size_t bytes) {
        char* r = p;
        p += (bytes + 255) & ~(size_t)255;
        return r;
    };
    float* xl    = (float*)carve((size_t)NN * 128 * 4);
    float* xr    = (float*)carve((size_t)NN * 128 * 4);
    float* resid = (float*)carve((size_t)NN * 128 * 4);
    float* h1    = (float*)carve((size_t)NN * 128 * 4);
    float* score = (float*)carve((size_t)NE * 4 * 4);
    int* off     = (int*)carve((size_t)(NN + 1) * 4);
    int* cur     = (int*)carve((size_t)NN * 4);
    int* csr_src = (int*)carve((size_t)NE * 4);
    int* csr_eid = (int*)carve((size_t)NE * 4);

    // CSR build (edge_index constant across both layers)
    hipMemsetAsync(cur, 0, (size_t)NN * 4, stream);
    k_count<<<(NE + 255) / 256, 256, 0, stream>>>(dstv, cur);
    k_scan<<<1, 1024, 0, stream>>>(cur, off);
    k_copyoff<<<(NN + 255) / 256, 256, 0, stream>>>(off, cur);
    k_scatter<<<(NE + 255) / 256, 256, 0, stream>>>(srcv, dstv, cur, csr_src, csr_eid);

    int gblocks = (NN + 63) / 64;
    // layer 1 node transforms + residual
    k_gemm128<<<gblocks, 256, 0, stream>>>(x, Wl1, bl1, xl, NN, DIN);
    k_gemm128<<<gblocks, 256, 0, stream>>>(x, Wr1, br1, xr, NN, DIN);
    k_gemm128<<<gblocks, 256, 0, stream>>>(x, Wres, bres, resid, NN, DIN);
    // layer 1 edges + aggregate (+bias,ELU,residual,LN) -> h1
    k_edge_score<<<(NE * 4 + 255) / 256, 256, 0, stream>>>(xl, xr, ea, We1, att1, srcv, dstv, score);
    k_node_agg<<<NN, 128, 0, stream>>>(off, csr_src, csr_eid, score, xl, resid, bias1, g1, bn1, h1);
    // layer 2
    k_gemm128<<<gblocks, 256, 0, stream>>>(h1, Wl2, bl2, xl, NN, HID);
    k_gemm128<<<gblocks, 256, 0, stream>>>(h1, Wr2, br2, xr, NN, HID);
    k_edge_score<<<(NE * 4 + 255) / 256, 256, 0, stream>>>(xl, xr, ea, We2, att2, srcv, dstv, score);
    k_node_agg<<<NN, 128, 0, stream>>>(off, csr_src, csr_eid, score, xl, h1, bias2, g2, bn2, resid);
    // output projection + LN
    k_gemm128<<<gblocks, 256, 0, stream>>>(resid, Wout, bout, xl, NN, HID);
    k_ln<<<NN, 128, 0, stream>>>(xl, go, bo, outp);
}

// Round 2
// 935.826 us; speedup vs baseline: 1.0977x; 1.0977x over previous
//
#include <hip/hip_runtime.h>
#include <hip/hip_bf16.h>
#include <math.h>
#include <stdint.h>

#define NN 50000
#define NE 500000
#define DIN 264
#define KP1 288      // DIN padded to multiple of 32
#define HID 128
#define EDIM 16

typedef __attribute__((ext_vector_type(8))) short short8;
typedef __attribute__((ext_vector_type(4))) float f32x4;

__device__ __forceinline__ short f2bf(float v) {
    union { float f; unsigned u; } x; x.f = v;
    unsigned r = x.u + 0x7fff + ((x.u >> 16) & 1);
    return (short)(r >> 16);
}

__device__ __forceinline__ void gload_lds16(const void* g, void* l) {
    __builtin_amdgcn_global_load_lds(
        (const __attribute__((address_space(1))) unsigned int*)g,
        (__attribute__((address_space(3))) unsigned int*)l, 16, 0, 0);
}

// ---------------- CSR build (dst -> in-edges) ----------------
__global__ void k_count(const int* __restrict__ dst, int* __restrict__ cnt) {
    int e = blockIdx.x * blockDim.x + threadIdx.x;
    if (e < NE) atomicAdd(&cnt[dst[e]], 1);
}

__global__ __launch_bounds__(256) void k_scan1(const int* __restrict__ cnt,
                                               int* __restrict__ off, int* __restrict__ bsum) {
    __shared__ int buf[256];
    int b = blockIdx.x, t = threadIdx.x;
    int i = b * 256 + t;
    int v = (i < NN) ? cnt[i] : 0;
    buf[t] = v; __syncthreads();
    for (int s = 1; s < 256; s <<= 1) {
        int u = (t >= s) ? buf[t - s] : 0; __syncthreads();
        buf[t] += u; __syncthreads();
    }
    if (i < NN) off[i + 1] = buf[t];
    if (t == 255) bsum[b] = buf[255];
}

__global__ void k_scan2(int* __restrict__ bsum, int nb) {
    __shared__ int buf[256];
    int t = threadIdx.x;
    int o = (t < nb) ? bsum[t] : 0;
    buf[t] = o; __syncthreads();
    for (int s = 1; s < 256; s <<= 1) {
        int u = (t >= s) ? buf[t - s] : 0; __syncthreads();
        buf[t] += u; __syncthreads();
    }
    if (t < nb) bsum[t] = buf[t] - o;   // exclusive
}

__global__ void k_scan3(int* __restrict__ off, const int* __restrict__ bsum) {
    int i = blockIdx.x * 256 + threadIdx.x;
    if (i < NN) off[i + 1] += bsum[i >> 8];
    if (i == 0) off[0] = 0;
}

__global__ void k_copyoff(const int* __restrict__ off, int* __restrict__ cur) {
    int i = blockIdx.x * blockDim.x + threadIdx.x;
    if (i < NN) cur[i] = off[i];
}

__global__ void k_scatter(const int* __restrict__ src, const int* __restrict__ dst,
                          int* __restrict__ cur, int* __restrict__ csr_src,
                          int* __restrict__ csr_eid) {
    int e = blockIdx.x * blockDim.x + threadIdx.x;
    if (e < NE) {
        int p = atomicAdd(&cur[dst[e]], 1);
        csr_src[p] = src[e];
        csr_eid[p] = e;
    }
}

// ---------------- weight/bias/input prep ----------------
__global__ void k_cvt_x(const float* __restrict__ x, short* __restrict__ xb) {
    int idx = blockIdx.x * 256 + threadIdx.x;
    if (idx >= NN * KP1) return;
    int i = idx / KP1, k = idx - i * KP1;
    xb[idx] = (k < DIN) ? f2bf(x[(size_t)i * DIN + k]) : (short)0;
}

__global__ void k_build_bt1(const float* __restrict__ Wl, const float* __restrict__ Wr,
                            const float* __restrict__ Wres, short* __restrict__ Bt) {
    int idx = blockIdx.x * 256 + threadIdx.x;   // 384*288
    if (idx >= 384 * KP1) return;
    int n = idx / KP1, k = idx - n * KP1;
    float v = 0.f;
    if (k < DIN) {
        const float* W = (n < 128) ? Wl : ((n < 256) ? Wr : Wres);
        v = W[(size_t)k * 128 + (n & 127)];
    }
    Bt[idx] = f2bf(v);
}

__global__ void k_build_bt2(const float* __restrict__ Wl, const float* __restrict__ Wr,
                            short* __restrict__ Bt) {
    int idx = blockIdx.x * 256 + threadIdx.x;   // 256*128
    if (idx >= 256 * 128) return;
    int n = idx >> 7, k = idx & 127;
    const float* W = (n < 128) ? Wl : Wr;
    Bt[idx] = f2bf(W[(size_t)k * 128 + (n & 127)]);
}

__global__ void k_build_bt3(const float* __restrict__ W, short* __restrict__ Bt) {
    int idx = blockIdx.x * 256 + threadIdx.x;   // 128*128
    if (idx >= 128 * 128) return;
    int n = idx >> 7, k = idx & 127;
    Bt[idx] = f2bf(W[(size_t)k * 128 + n]);
}

__global__ void k_cat3(const float* a, const float* b, const float* c, float* o) {
    int t = threadIdx.x;   // 384
    o[t] = (t < 128) ? a[t] : ((t < 256) ? b[t - 128] : c[t - 256]);
}

__global__ void k_cat2(const float* a, const float* b, float* o) {
    int t = threadIdx.x;   // 256
    o[t] = (t < 128) ? a[t] : b[t - 128];
}

// ---------------- bf16 MFMA GEMM: C[M x NS] = A[M x Kpad] @ Bt[NS x Kpad]^T + bias ----------------
// 128x128 tile, 256 threads (4 waves, 2x2), each wave 4x4 MFMAs of 16x16x32
__global__ __launch_bounds__(256) void k_mfma_gemm(const short* __restrict__ A,
                                                   const short* __restrict__ Bt,
                                                   const float* __restrict__ bias,
                                                   float* __restrict__ C,
                                                   int M, int Kpad, int NS) {
    __shared__ short As[128 * 32];
    __shared__ short Bs[128 * 32];
    int t = threadIdx.x;
    int lane = t & 63, wid = t >> 6;
    int wm = (wid & 1) * 64, wn = (wid >> 1) * 64;
    int cl = lane & 15, quad = lane >> 4;
    int row0 = blockIdx.x * 128;
    int col0 = blockIdx.y * 128;

    f32x4 acc[4][4];
#pragma unroll
    for (int i = 0; i < 4; ++i)
#pragma unroll
        for (int j = 0; j < 4; ++j) acc[i][j] = (f32x4)0.f;

    for (int k0 = 0; k0 < Kpad; k0 += 32) {
#pragma unroll
        for (int r = 0; r < 2; ++r) {
            int c = t + r * 256;                     // chunk 0..511
            int m = c >> 2;
            int row = row0 + m; if (row >= M) row = M - 1;
            const char* ga = (const char*)A + ((size_t)row * Kpad + k0) * 2 + (c & 3) * 16;
            gload_lds16(ga, (char*)As + c * 16);
            int n = col0 + m;
            const char* gb = (const char*)Bt + ((size_t)n * Kpad + k0) * 2 + (c & 3) * 16;
            gload_lds16(gb, (char*)Bs + c * 16);
        }
        __syncthreads();

        short8 a[4], b[4];
#pragma unroll
        for (int mi = 0; mi < 4; ++mi)
            a[mi] = *(const short8*)&As[(wm + mi * 16 + cl) * 32 + quad * 8];
#pragma unroll
        for (int ni = 0; ni < 4; ++ni)
            b[ni] = *(const short8*)&Bs[(wn + ni * 16 + cl) * 32 + quad * 8];
#pragma unroll
        for (int mi = 0; mi < 4; ++mi)
#pragma unroll
            for (int ni = 0; ni < 4; ++ni)
                acc[mi][ni] = __builtin_amdgcn_mfma_f32_16x16x32_bf16(a[mi], b[ni], acc[mi][ni], 0, 0, 0);
        __syncthreads();
    }

#pragma unroll
    for (int mi = 0; mi < 4; ++mi)
#pragma unroll
        for (int ni = 0; ni < 4; ++ni) {
            int col = col0 + wn + ni * 16 + cl;
            float bv = bias[col];
#pragma unroll
            for (int r = 0; r < 4; ++r) {
                int row = row0 + wm + mi * 16 + quad * 4 + r;
                if (row < M) C[(size_t)row * NS + col] = acc[mi][ni][r] + bv;
            }
        }
}

// ---------------- edge scoring: wave-uniform head, scalar We/att loads ----------------
__global__ __launch_bounds__(256) void k_edge_score(const float* __restrict__ xl,
                                                    const float* __restrict__ xr,
                                                    int stride,
                                                    const float* __restrict__ ea,
                                                    const float* __restrict__ We,
                                                    const float* __restrict__ att,
                                                    const int* __restrict__ src,
                                                    const int* __restrict__ dst,
                                                    float* __restrict__ score) {
    int t = threadIdx.x;
    int h = __builtin_amdgcn_readfirstlane(t >> 6);   // wave-uniform head
    int e = blockIdx.x * 64 + (t & 63);
    if (e >= NE) return;

    float eav[EDIM];
#pragma unroll
    for (int j = 0; j < EDIM / 4; ++j) {
        float4 v = *reinterpret_cast<const float4*>(&ea[(size_t)e * EDIM + j * 4]);
        eav[j * 4 + 0] = v.x; eav[j * 4 + 1] = v.y;
        eav[j * 4 + 2] = v.z; eav[j * 4 + 3] = v.w;
    }
    const float4* xl4 = reinterpret_cast<const float4*>(&xl[(size_t)src[e] * stride + h * 32]);
    const float4* xr4 = reinterpret_cast<const float4*>(&xr[(size_t)dst[e] * stride + h * 32]);
    float m[32];
#pragma unroll
    for (int j = 0; j < 8; ++j) {
        float4 a = xl4[j], b = xr4[j];
        m[j * 4 + 0] = a.x + b.x; m[j * 4 + 1] = a.y + b.y;
        m[j * 4 + 2] = a.z + b.z; m[j * 4 + 3] = a.w + b.w;
    }
    const float* wrow = We + h * 32;                 // wave-uniform -> s_load
#pragma unroll
    for (int k = 0; k < EDIM; ++k) {
        float a = eav[k];
        const float* w = wrow + k * 128;
#pragma unroll
        for (int c = 0; c < 32; ++c) m[c] += a * w[c];
    }
    const float* at = att + h * 32;                  // wave-uniform -> s_load
    float s = 0.f;
#pragma unroll
    for (int c = 0; c < 32; ++c) {
        float g = m[c] > 0.f ? m[c] : 0.2f * m[c];
        s += g * at[c];
    }
    score[(size_t)h * NE + e] = s;                   // coalesced per wave
}

// ---------------- block helpers ----------------
__device__ __forceinline__ float block_sum128(float v, volatile float* red) {
#pragma unroll
    for (int o = 32; o > 0; o >>= 1) v += __shfl_down(v, o, 64);
    int w = threadIdx.x >> 6;
    __syncthreads();
    if ((threadIdx.x & 63) == 0) red[w] = v;
    __syncthreads();
    return red[0] + red[1];
}

// ---------------- per-node softmax + aggregate + bias + ELU + residual + LN ----------------
__global__ __launch_bounds__(128) void k_node_agg(const int* __restrict__ off,
                                                  const int* __restrict__ csr_src,
                                                  const int* __restrict__ csr_eid,
                                                  const float* __restrict__ score,
                                                  const float* __restrict__ xl, int xls,
                                                  const float* __restrict__ residual, int rs,
                                                  const float* __restrict__ bias,
                                                  const float* __restrict__ gamma,
                                                  const float* __restrict__ beta,
                                                  float* __restrict__ out,
                                                  short* __restrict__ outb) {
    __shared__ float red[2];
    int i = blockIdx.x;
    int t = threadIdx.x;
    int h = t >> 5;
    int b0 = off[i], b1 = off[i + 1];

    float mx = -INFINITY;
    for (int k = b0; k < b1; ++k)
        mx = fmaxf(mx, score[(size_t)h * NE + csr_eid[k]]);

    float denom = 0.f, acc = 0.f;
    for (int k = b0; k < b1; ++k) {
        int e = csr_eid[k];
        int s = csr_src[k];
        float ex = __expf(score[(size_t)h * NE + e] - mx);
        denom += ex;
        acc += ex * xl[(size_t)s * xls + t];
    }
    float o = acc / (denom + 1e-16f) + bias[t];
    o = o > 0.f ? o : (__expf(o) - 1.f);                 // ELU
    float v = o + residual[(size_t)i * rs + t];          // + residual
    float mean = block_sum128(v, red) * (1.f / 128.f);
    float d = v - mean;
    float var = block_sum128(d * d, red) * (1.f / 128.f);
    float r = d * rsqrtf(var + 1e-5f) * gamma[t] + beta[t];
    out[(size_t)i * 128 + t] = r;
    outb[(size_t)i * 128 + t] = f2bf(r);
}

// ---------------- plain LN over 128 ----------------
__global__ __launch_bounds__(128) void k_ln(const float* __restrict__ in,
                                            const float* __restrict__ gamma,
                                            const float* __restrict__ beta,
                                            float* __restrict__ out) {
    __shared__ float red[2];
    int i = blockIdx.x, t = threadIdx.x;
    float v = in[(size_t)i * 128 + t];
    float mean = block_sum128(v, red) * (1.f / 128.f);
    float d = v - mean;
    float var = block_sum128(d * d, red) * (1.f / 128.f);
    out[(size_t)i * 128 + t] = d * rsqrtf(var + 1e-5f) * gamma[t] + beta[t];
}

extern "C" void kernel_launch(void* const* d_in, const int* in_sizes, int n_in,
                              void* d_out, int out_size, void* d_ws, size_t ws_size,
                              hipStream_t stream) {
    (void)in_sizes; (void)n_in; (void)out_size; (void)ws_size;
    const float* x     = (const float*)d_in[0];
    const float* ea    = (const float*)d_in[1];
    const float* Wl1   = (const float*)d_in[2];
    const float* bl1   = (const float*)d_in[3];
    const float* Wr1   = (const float*)d_in[4];
    const float* br1   = (const float*)d_in[5];
    const float* We1   = (const float*)d_in[6];
    const float* att1  = (const float*)d_in[7];
    const float* bias1 = (const float*)d_in[8];
    const float* Wl2   = (const float*)d_in[9];
    const float* bl2   = (const float*)d_in[10];
    const float* Wr2   = (const float*)d_in[11];
    const float* br2   = (const float*)d_in[12];
    const float* We2   = (const float*)d_in[13];
    const float* att2  = (const float*)d_in[14];
    const float* bias2 = (const float*)d_in[15];
    const float* Wres  = (const float*)d_in[16];
    const float* bres  = (const float*)d_in[17];
    const float* Wout  = (const float*)d_in[18];
    const float* bout  = (const float*)d_in[19];
    const float* g1    = (const float*)d_in[20];
    const float* bn1   = (const float*)d_in[21];
    const float* g2    = (const float*)d_in[22];
    const float* bn2   = (const float*)d_in[23];
    const float* go    = (const float*)d_in[24];
    const float* bo    = (const float*)d_in[25];
    const int*   ei    = (const int*)d_in[26];
    const int* srcv = ei;
    const int* dstv = ei + NE;
    float* outp = (float*)d_out;

    char* p = (char*)d_ws;
    auto carve = [&](size_t bytes) {
        char* r = p;
        p += (bytes + 255) & ~(size_t)255;
        return r;
    };
    short* xb    = (short*)carve((size_t)NN * KP1 * 2);
    short* Wt1   = (short*)carve((size_t)384 * KP1 * 2);
    short* Wt2   = (short*)carve((size_t)256 * 128 * 2);
    short* Wt3   = (short*)carve((size_t)128 * 128 * 2);
    float* bcat1 = (float*)carve(384 * 4);
    float* bcat2 = (float*)carve(256 * 4);
    float* C1    = (float*)carve((size_t)NN * 384 * 4);   // layer1 [xl|xr|res]; reused as C2/C3
    float* h1    = (float*)carve((size_t)NN * 128 * 4);
    short* h1b   = (short*)carve((size_t)NN * 128 * 2);
    short* h2b   = (short*)carve((size_t)NN * 128 * 2);
    float* score = (float*)carve((size_t)NE * 4 * 4);
    int* off     = (int*)carve((size_t)(NN + 1) * 4);
    int* cur     = (int*)carve((size_t)NN * 4);
    int* bsum    = (int*)carve(256 * 4);
    int* csr_src = (int*)carve((size_t)NE * 4);
    int* csr_eid = (int*)carve((size_t)NE * 4);

    float* C2 = C1;                                  // stride 256, reuse after node_agg1
    float* C3 = C1 + (size_t)NN * 256;               // stride 128, free region of C1

    const int NB = (NN + 255) / 256;                 // 196

    // ---- CSR build ----
    hipMemsetAsync(cur, 0, (size_t)NN * 4, stream);
    k_count<<<(NE + 255) / 256, 256, 0, stream>>>(dstv, cur);
    k_scan1<<<NB, 256, 0, stream>>>(cur, off, bsum);
    k_scan2<<<1, 256, 0, stream>>>(bsum, NB);
    k_scan3<<<NB, 256, 0, stream>>>(off, bsum);
    k_copyoff<<<NB, 256, 0, stream>>>(off, cur);
    k_scatter<<<(NE + 255) / 256, 256, 0, stream>>>(srcv, dstv, cur, csr_src, csr_eid);

    // ---- prep ----
    k_cvt_x<<<((size_t)NN * KP1 + 255) / 256, 256, 0, stream>>>(x, xb);
    k_build_bt1<<<(384 * KP1 + 255) / 256, 256, 0, stream>>>(Wl1, Wr1, Wres, Wt1);
    k_build_bt2<<<(256 * 128 + 255) / 256, 256, 0, stream>>>(Wl2, Wr2, Wt2);
    k_build_bt3<<<(128 * 128 + 255) / 256, 256, 0, stream>>>(Wout, Wt3);
    k_cat3<<<1, 384, 0, stream>>>(bl1, br1, bres, bcat1);
    k_cat2<<<1, 256, 0, stream>>>(bl2, br2, bcat2);

    int mb = (NN + 127) / 128;                       // 391

    // ---- layer 1 ----
    k_mfma_gemm<<<dim3(mb, 3), 256, 0, stream>>>(xb, Wt1, bcat1, C1, NN, KP1, 384);
    k_edge_score<<<(NE + 63) / 64, 256, 0, stream>>>(C1, C1 + 128, 384, ea, We1, att1, srcv, dstv, score);
    k_node_agg<<<NN, 128, 0, stream>>>(off, csr_src, csr_eid, score, C1, 384, C1 + 256, 384,
                                       bias1, g1, bn1, h1, h1b);
    // ---- layer 2 ----
    k_mfma_gemm<<<dim3(mb, 2), 256, 0, stream>>>(h1b, Wt2, bcat2, C2, NN, 128, 256);
    k_edge_score<<<(NE + 63) / 64, 256, 0, stream>>>(C2, C2 + 128, 256, ea, We2, att2, srcv, dstv, score);
    k_node_agg<<<NN, 128, 0, stream>>>(off, csr_src, csr_eid, score, C2, 256, h1, 128,
                                       bias2, g2, bn2, h1, h2b);
    // ---- output ----
    k_mfma_gemm<<<dim3(mb, 1), 256, 0, stream>>>(h2b, Wt3, bout, C3, NN, 128, 128);
    k_ln<<<NN, 128, 0, stream>>>(C3, go, bo, outp);
}

// Round 3
// 736.720 us; speedup vs baseline: 1.3944x; 1.2703x over previous
//
#include <hip/hip_runtime.h>
#include <hip/hip_bf16.h>
#include <math.h>
#include <stdint.h>

#define NN 50000
#define NE 500000
#define DIN 264
#define KP1 288      // DIN padded to multiple of 32
#define HID 128
#define EDIM 16

typedef __attribute__((ext_vector_type(8))) short short8;
typedef __attribute__((ext_vector_type(4))) float f32x4;

__device__ __forceinline__ short f2bf(float v) {
    union { float f; unsigned u; } x; x.f = v;
    unsigned r = x.u + 0x7fff + ((x.u >> 16) & 1);
    return (short)(r >> 16);
}

__device__ __forceinline__ void gload_lds16(const void* g, void* l) {
    __builtin_amdgcn_global_load_lds(
        (const __attribute__((address_space(1))) unsigned int*)g,
        (__attribute__((address_space(3))) unsigned int*)l, 16, 0, 0);
}

// ---------------- CSR build (dst -> in-edges) ----------------
__global__ void k_count(const int* __restrict__ dst, int* __restrict__ cnt) {
    int e = blockIdx.x * blockDim.x + threadIdx.x;
    if (e < NE) atomicAdd(&cnt[dst[e]], 1);
}

__global__ __launch_bounds__(256) void k_scan1(const int* __restrict__ cnt,
                                               int* __restrict__ off, int* __restrict__ bsum) {
    __shared__ int buf[256];
    int b = blockIdx.x, t = threadIdx.x;
    int i = b * 256 + t;
    int v = (i < NN) ? cnt[i] : 0;
    buf[t] = v; __syncthreads();
    for (int s = 1; s < 256; s <<= 1) {
        int u = (t >= s) ? buf[t - s] : 0; __syncthreads();
        buf[t] += u; __syncthreads();
    }
    if (i < NN) off[i + 1] = buf[t];
    if (t == 255) bsum[b] = buf[255];
}

__global__ void k_scan2(int* __restrict__ bsum, int nb) {
    __shared__ int buf[256];
    int t = threadIdx.x;
    int o = (t < nb) ? bsum[t] : 0;
    buf[t] = o; __syncthreads();
    for (int s = 1; s < 256; s <<= 1) {
        int u = (t >= s) ? buf[t - s] : 0; __syncthreads();
        buf[t] += u; __syncthreads();
    }
    if (t < nb) bsum[t] = buf[t] - o;   // exclusive
}

__global__ void k_scan3(int* __restrict__ off, const int* __restrict__ bsum) {
    int i = blockIdx.x * 256 + threadIdx.x;
    if (i < NN) off[i + 1] += bsum[i >> 8];
    if (i == 0) off[0] = 0;
}

__global__ void k_copyoff(const int* __restrict__ off, int* __restrict__ cur) {
    int i = blockIdx.x * blockDim.x + threadIdx.x;
    if (i < NN) cur[i] = off[i];
}

__global__ void k_scatter(const int* __restrict__ src, const int* __restrict__ dst,
                          int* __restrict__ cur, int* __restrict__ csr_src,
                          int* __restrict__ csr_dst, int* __restrict__ csr_eid) {
    int e = blockIdx.x * blockDim.x + threadIdx.x;
    if (e < NE) {
        int d = dst[e];
        int p = atomicAdd(&cur[d], 1);
        csr_src[p] = src[e];
        csr_dst[p] = d;
        csr_eid[p] = e;
    }
}

// ---------------- weight/bias/input prep ----------------
__global__ void k_cvt_x(const float* __restrict__ x, short* __restrict__ xb) {
    int idx = blockIdx.x * 256 + threadIdx.x;
    if (idx >= NN * KP1) return;
    int i = idx / KP1, k = idx - i * KP1;
    xb[idx] = (k < DIN) ? f2bf(x[(size_t)i * DIN + k]) : (short)0;
}

__global__ void k_build_bt1(const float* __restrict__ Wl, const float* __restrict__ Wr,
                            const float* __restrict__ Wres, short* __restrict__ Bt) {
    int idx = blockIdx.x * 256 + threadIdx.x;   // 384*288
    if (idx >= 384 * KP1) return;
    int n = idx / KP1, k = idx - n * KP1;
    float v = 0.f;
    if (k < DIN) {
        const float* W = (n < 128) ? Wl : ((n < 256) ? Wr : Wres);
        v = W[(size_t)k * 128 + (n & 127)];
    }
    Bt[idx] = f2bf(v);
}

__global__ void k_build_bt2(const float* __restrict__ Wl, const float* __restrict__ Wr,
                            short* __restrict__ Bt) {
    int idx = blockIdx.x * 256 + threadIdx.x;   // 256*128
    if (idx >= 256 * 128) return;
    int n = idx >> 7, k = idx & 127;
    const float* W = (n < 128) ? Wl : Wr;
    Bt[idx] = f2bf(W[(size_t)k * 128 + (n & 127)]);
}

__global__ void k_build_bt3(const float* __restrict__ W, short* __restrict__ Bt) {
    int idx = blockIdx.x * 256 + threadIdx.x;   // 128*128
    if (idx >= 128 * 128) return;
    int n = idx >> 7, k = idx & 127;
    Bt[idx] = f2bf(W[(size_t)k * 128 + n]);
}

__global__ void k_cat3(const float* a, const float* b, const float* c, float* o) {
    int t = threadIdx.x;   // 384
    o[t] = (t < 128) ? a[t] : ((t < 256) ? b[t - 128] : c[t - 256]);
}

__global__ void k_cat2(const float* a, const float* b, float* o) {
    int t = threadIdx.x;   // 256
    o[t] = (t < 128) ? a[t] : b[t - 128];
}

// ---------------- bf16 MFMA GEMM: C[M x NS] = A[M x Kpad] @ Bt[NS x Kpad]^T + bias ----------------
__global__ __launch_bounds__(256) void k_mfma_gemm(const short* __restrict__ A,
                                                   const short* __restrict__ Bt,
                                                   const float* __restrict__ bias,
                                                   float* __restrict__ C,
                                                   int M, int Kpad, int NS) {
    __shared__ short As[128 * 32];
    __shared__ short Bs[128 * 32];
    int t = threadIdx.x;
    int lane = t & 63, wid = t >> 6;
    int wm = (wid & 1) * 64, wn = (wid >> 1) * 64;
    int cl = lane & 15, quad = lane >> 4;
    int row0 = blockIdx.x * 128;
    int col0 = blockIdx.y * 128;

    f32x4 acc[4][4];
#pragma unroll
    for (int i = 0; i < 4; ++i)
#pragma unroll
        for (int j = 0; j < 4; ++j) acc[i][j] = (f32x4)0.f;

    for (int k0 = 0; k0 < Kpad; k0 += 32) {
#pragma unroll
        for (int r = 0; r < 2; ++r) {
            int c = t + r * 256;                     // chunk 0..511
            int m = c >> 2;
            int row = row0 + m; if (row >= M) row = M - 1;
            const char* ga = (const char*)A + ((size_t)row * Kpad + k0) * 2 + (c & 3) * 16;
            gload_lds16(ga, (char*)As + c * 16);
            int n = col0 + m;
            const char* gb = (const char*)Bt + ((size_t)n * Kpad + k0) * 2 + (c & 3) * 16;
            gload_lds16(gb, (char*)Bs + c * 16);
        }
        __syncthreads();

        short8 a[4], b[4];
#pragma unroll
        for (int mi = 0; mi < 4; ++mi)
            a[mi] = *(const short8*)&As[(wm + mi * 16 + cl) * 32 + quad * 8];
#pragma unroll
        for (int ni = 0; ni < 4; ++ni)
            b[ni] = *(const short8*)&Bs[(wn + ni * 16 + cl) * 32 + quad * 8];
#pragma unroll
        for (int mi = 0; mi < 4; ++mi)
#pragma unroll
            for (int ni = 0; ni < 4; ++ni)
                acc[mi][ni] = __builtin_amdgcn_mfma_f32_16x16x32_bf16(a[mi], b[ni], acc[mi][ni], 0, 0, 0);
        __syncthreads();
    }

#pragma unroll
    for (int mi = 0; mi < 4; ++mi)
#pragma unroll
        for (int ni = 0; ni < 4; ++ni) {
            int col = col0 + wn + ni * 16 + cl;
            float bv = bias[col];
#pragma unroll
            for (int r = 0; r < 4; ++r) {
                int row = row0 + wm + mi * 16 + quad * 4 + r;
                if (row < M) C[(size_t)row * NS + col] = acc[mi][ni][r] + bv;
            }
        }
}

// ---------------- edge scoring: CSR order, 4 lanes per edge, conflict-free LDS ----------------
// score[pos*4+h] = sum_c leaky(xl[src][h,c] + xr[dst][h,c] + (ea @ We)[h,c]) * att[h,c]
__global__ __launch_bounds__(256) void k_edge_score(const float* __restrict__ xl,
                                                    const float* __restrict__ xr,
                                                    int stride,
                                                    const float* __restrict__ ea,
                                                    const float* __restrict__ We,
                                                    const float* __restrict__ att,
                                                    const int* __restrict__ csr_src,
                                                    const int* __restrict__ csr_dst,
                                                    const int* __restrict__ csr_eid,
                                                    float* __restrict__ score) {
    // transposed layouts: [k][c][h] so lanes (h=lane&3) hit 4 adjacent banks, broadcast
    __shared__ float sWeT[EDIM * 32 * 4];
    __shared__ float sAttT[32 * 4];
    for (int i = threadIdx.x; i < EDIM * 128; i += 256) {
        int k = i >> 7, r = i & 127;
        int h = r >> 5, c = r & 31;
        sWeT[(k * 32 + c) * 4 + h] = We[i];
    }
    if (threadIdx.x < 128) {
        int h = threadIdx.x >> 5, c = threadIdx.x & 31;
        sAttT[c * 4 + h] = att[threadIdx.x];
    }
    __syncthreads();

    int gid = blockIdx.x * 256 + threadIdx.x;
    int pos = gid >> 2, h = gid & 3;
    if (pos >= NE) return;
    int s = csr_src[pos];
    int d = csr_dst[pos];
    int e = csr_eid[pos];

    float eav[EDIM];
#pragma unroll
    for (int j = 0; j < EDIM / 4; ++j) {
        float4 v = *reinterpret_cast<const float4*>(&ea[(size_t)e * EDIM + j * 4]);
        eav[j * 4 + 0] = v.x; eav[j * 4 + 1] = v.y;
        eav[j * 4 + 2] = v.z; eav[j * 4 + 3] = v.w;
    }
    const float4* xl4 = reinterpret_cast<const float4*>(&xl[(size_t)s * stride + h * 32]);
    const float4* xr4 = reinterpret_cast<const float4*>(&xr[(size_t)d * stride + h * 32]);
    float m[32];
#pragma unroll
    for (int j = 0; j < 8; ++j) {
        float4 a = xl4[j], b = xr4[j];
        m[j * 4 + 0] = a.x + b.x; m[j * 4 + 1] = a.y + b.y;
        m[j * 4 + 2] = a.z + b.z; m[j * 4 + 3] = a.w + b.w;
    }
#pragma unroll
    for (int k = 0; k < EDIM; ++k) {
        float a = eav[k];
        const float* w = &sWeT[k * 128 + h];
#pragma unroll
        for (int c = 0; c < 32; ++c) m[c] += a * w[c * 4];
    }
    float sc = 0.f;
#pragma unroll
    for (int c = 0; c < 32; ++c) {
        float g = m[c] > 0.f ? m[c] : 0.2f * m[c];
        sc += g * sAttT[c * 4 + h];
    }
    score[(size_t)pos * 4 + h] = sc;   // fully coalesced
}

// ---------------- block helpers ----------------
__device__ __forceinline__ float block_sum128(float v, volatile float* red) {
#pragma unroll
    for (int o = 32; o > 0; o >>= 1) v += __shfl_down(v, o, 64);
    int w = threadIdx.x >> 6;
    __syncthreads();
    if ((threadIdx.x & 63) == 0) red[w] = v;
    __syncthreads();
    return red[0] + red[1];
}

// ---------------- per-node softmax + aggregate + bias + ELU + residual + LN ----------------
__global__ __launch_bounds__(128) void k_node_agg(const int* __restrict__ off,
                                                  const int* __restrict__ csr_src,
                                                  const float* __restrict__ score,
                                                  const float* __restrict__ xl, int xls,
                                                  const float* __restrict__ residual, int rs,
                                                  const float* __restrict__ bias,
                                                  const float* __restrict__ gamma,
                                                  const float* __restrict__ beta,
                                                  float* __restrict__ out,
                                                  short* __restrict__ outb) {
    __shared__ float red[2];
    int i = blockIdx.x;
    int t = threadIdx.x;
    int h = t >> 5;
    int b0 = off[i], b1 = off[i + 1];

    float mx = -INFINITY;
    for (int pos = b0; pos < b1; ++pos)
        mx = fmaxf(mx, score[(size_t)pos * 4 + h]);

    float denom = 0.f, acc = 0.f;
    for (int pos = b0; pos < b1; ++pos) {
        int s = csr_src[pos];
        float ex = __expf(score[(size_t)pos * 4 + h] - mx);
        denom += ex;
        acc += ex * xl[(size_t)s * xls + t];
    }
    float o = acc / (denom + 1e-16f) + bias[t];
    o = o > 0.f ? o : (__expf(o) - 1.f);                 // ELU
    float v = o + residual[(size_t)i * rs + t];          // + residual
    float mean = block_sum128(v, red) * (1.f / 128.f);
    float d = v - mean;
    float var = block_sum128(d * d, red) * (1.f / 128.f);
    float r = d * rsqrtf(var + 1e-5f) * gamma[t] + beta[t];
    out[(size_t)i * 128 + t] = r;
    outb[(size_t)i * 128 + t] = f2bf(r);
}

// ---------------- plain LN over 128 ----------------
__global__ __launch_bounds__(128) void k_ln(const float* __restrict__ in,
                                            const float* __restrict__ gamma,
                                            const float* __restrict__ beta,
                                            float* __restrict__ out) {
    __shared__ float red[2];
    int i = blockIdx.x, t = threadIdx.x;
    float v = in[(size_t)i * 128 + t];
    float mean = block_sum128(v, red) * (1.f / 128.f);
    float d = v - mean;
    float var = block_sum128(d * d, red) * (1.f / 128.f);
    out[(size_t)i * 128 + t] = d * rsqrtf(var + 1e-5f) * gamma[t] + beta[t];
}

extern "C" void kernel_launch(void* const* d_in, const int* in_sizes, int n_in,
                              void* d_out, int out_size, void* d_ws, size_t ws_size,
                              hipStream_t stream) {
    (void)in_sizes; (void)n_in; (void)out_size; (void)ws_size;
    const float* x     = (const float*)d_in[0];
    const float* ea    = (const float*)d_in[1];
    const float* Wl1   = (const float*)d_in[2];
    const float* bl1   = (const float*)d_in[3];
    const float* Wr1   = (const float*)d_in[4];
    const float* br1   = (const float*)d_in[5];
    const float* We1   = (const float*)d_in[6];
    const float* att1  = (const float*)d_in[7];
    const float* bias1 = (const float*)d_in[8];
    const float* Wl2   = (const float*)d_in[9];
    const float* bl2   = (const float*)d_in[10];
    const float* Wr2   = (const float*)d_in[11];
    const float* br2   = (const float*)d_in[12];
    const float* We2   = (const float*)d_in[13];
    const float* att2  = (const float*)d_in[14];
    const float* bias2 = (const float*)d_in[15];
    const float* Wres  = (const float*)d_in[16];
    const float* bres  = (const float*)d_in[17];
    const float* Wout  = (const float*)d_in[18];
    const float* bout  = (const float*)d_in[19];
    const float* g1    = (const float*)d_in[20];
    const float* bn1   = (const float*)d_in[21];
    const float* g2    = (const float*)d_in[22];
    const float* bn2   = (const float*)d_in[23];
    const float* go    = (const float*)d_in[24];
    const float* bo    = (const float*)d_in[25];
    const int*   ei    = (const int*)d_in[26];
    const int* srcv = ei;
    const int* dstv = ei + NE;
    float* outp = (float*)d_out;

    char* p = (char*)d_ws;
    auto carve = [&](size_t bytes) {
        char* r = p;
        p += (bytes + 255) & ~(size_t)255;
        return r;
    };
    short* xb    = (short*)carve((size_t)NN * KP1 * 2);
    short* Wt1   = (short*)carve((size_t)384 * KP1 * 2);
    short* Wt2   = (short*)carve((size_t)256 * 128 * 2);
    short* Wt3   = (short*)carve((size_t)128 * 128 * 2);
    float* bcat1 = (float*)carve(384 * 4);
    float* bcat2 = (float*)carve(256 * 4);
    float* C1    = (float*)carve((size_t)NN * 384 * 4);
    float* h1    = (float*)carve((size_t)NN * 128 * 4);
    short* h1b   = (short*)carve((size_t)NN * 128 * 2);
    short* h2b   = (short*)carve((size_t)NN * 128 * 2);
    float* score = (float*)carve((size_t)NE * 4 * 4);
    int* off     = (int*)carve((size_t)(NN + 1) * 4);
    int* cur     = (int*)carve((size_t)NN * 4);
    int* bsum    = (int*)carve(256 * 4);
    int* csr_src = (int*)carve((size_t)NE * 4);
    int* csr_dst = (int*)carve((size_t)NE * 4);
    int* csr_eid = (int*)carve((size_t)NE * 4);

    float* C2 = C1;                                  // stride 256
    float* C3 = C1 + (size_t)NN * 256;               // stride 128

    const int NB = (NN + 255) / 256;                 // 196

    // ---- CSR build ----
    hipMemsetAsync(cur, 0, (size_t)NN * 4, stream);
    k_count<<<(NE + 255) / 256, 256, 0, stream>>>(dstv, cur);
    k_scan1<<<NB, 256, 0, stream>>>(cur, off, bsum);
    k_scan2<<<1, 256, 0, stream>>>(bsum, NB);
    k_scan3<<<NB, 256, 0, stream>>>(off, bsum);
    k_copyoff<<<NB, 256, 0, stream>>>(off, cur);
    k_scatter<<<(NE + 255) / 256, 256, 0, stream>>>(srcv, dstv, cur, csr_src, csr_dst, csr_eid);

    // ---- prep ----
    k_cvt_x<<<((size_t)NN * KP1 + 255) / 256, 256, 0, stream>>>(x, xb);
    k_build_bt1<<<(384 * KP1 + 255) / 256, 256, 0, stream>>>(Wl1, Wr1, Wres, Wt1);
    k_build_bt2<<<(256 * 128 + 255) / 256, 256, 0, stream>>>(Wl2, Wr2, Wt2);
    k_build_bt3<<<(128 * 128 + 255) / 256, 256, 0, stream>>>(Wout, Wt3);
    k_cat3<<<1, 384, 0, stream>>>(bl1, br1, bres, bcat1);
    k_cat2<<<1, 256, 0, stream>>>(bl2, br2, bcat2);

    int mb = (NN + 127) / 128;                       // 391
    int eb = (NE * 4 + 255) / 256;                   // 7813

    // ---- layer 1 ----
    k_mfma_gemm<<<dim3(mb, 3), 256, 0, stream>>>(xb, Wt1, bcat1, C1, NN, KP1, 384);
    k_edge_score<<<eb, 256, 0, stream>>>(C1, C1 + 128, 384, ea, We1, att1, csr_src, csr_dst, csr_eid, score);
    k_node_agg<<<NN, 128, 0, stream>>>(off, csr_src, score, C1, 384, C1 + 256, 384,
                                       bias1, g1, bn1, h1, h1b);
    // ---- layer 2 ----
    k_mfma_gemm<<<dim3(mb, 2), 256, 0, stream>>>(h1b, Wt2, bcat2, C2, NN, 128, 256);
    k_edge_score<<<eb, 256, 0, stream>>>(C2, C2 + 128, 256, ea, We2, att2, csr_src, csr_dst, csr_eid, score);
    k_node_agg<<<NN, 128, 0, stream>>>(off, csr_src, score, C2, 256, h1, 128,
                                       bias2, g2, bn2, h1, h2b);
    // ---- output ----
    k_mfma_gemm<<<dim3(mb, 1), 256, 0, stream>>>(h2b, Wt3, bout, C3, NN, 128, 128);
    k_ln<<<NN, 128, 0, stream>>>(C3, go, bo, outp);
}

// Round 4
// 594.564 us; speedup vs baseline: 1.7278x; 1.2391x over previous
//
#include <hip/hip_runtime.h>
#include <hip/hip_bf16.h>
#include <math.h>
#include <stdint.h>

#define NN 50000
#define NE 500000
#define DIN 264
#define KP1 288      // DIN padded to multiple of 32
#define HID 128
#define EDIM 16

typedef __attribute__((ext_vector_type(8))) short short8;
typedef __attribute__((ext_vector_type(4))) float f32x4;

__device__ __forceinline__ short f2bf(float v) {
    union { float f; unsigned u; } x; x.f = v;
    unsigned r = x.u + 0x7fff + ((x.u >> 16) & 1);
    return (short)(r >> 16);
}
__device__ __forceinline__ float bf2f(short v) {
    union { float f; unsigned u; } x;
    x.u = ((unsigned)(unsigned short)v) << 16;
    return x.f;
}

__device__ __forceinline__ void gload_lds16(const void* g, void* l) {
    __builtin_amdgcn_global_load_lds(
        (const __attribute__((address_space(1))) unsigned int*)g,
        (__attribute__((address_space(3))) unsigned int*)l, 16, 0, 0);
}

// ---------------- CSR build (dst -> in-edges) ----------------
__global__ void k_count(const int* __restrict__ dst, int* __restrict__ cnt) {
    int e = blockIdx.x * blockDim.x + threadIdx.x;
    if (e < NE) atomicAdd(&cnt[dst[e]], 1);
}

__global__ __launch_bounds__(256) void k_scan1(const int* __restrict__ cnt,
                                               int* __restrict__ off, int* __restrict__ bsum) {
    __shared__ int buf[256];
    int b = blockIdx.x, t = threadIdx.x;
    int i = b * 256 + t;
    int v = (i < NN) ? cnt[i] : 0;
    buf[t] = v; __syncthreads();
    for (int s = 1; s < 256; s <<= 1) {
        int u = (t >= s) ? buf[t - s] : 0; __syncthreads();
        buf[t] += u; __syncthreads();
    }
    if (i < NN) off[i + 1] = buf[t];
    if (t == 255) bsum[b] = buf[255];
}

__global__ void k_scan2(int* __restrict__ bsum, int nb) {
    __shared__ int buf[256];
    int t = threadIdx.x;
    int o = (t < nb) ? bsum[t] : 0;
    buf[t] = o; __syncthreads();
    for (int s = 1; s < 256; s <<= 1) {
        int u = (t >= s) ? buf[t - s] : 0; __syncthreads();
        buf[t] += u; __syncthreads();
    }
    if (t < nb) bsum[t] = buf[t] - o;   // exclusive
}

__global__ void k_scan3(int* __restrict__ off, const int* __restrict__ bsum) {
    int i = blockIdx.x * 256 + threadIdx.x;
    if (i < NN) off[i + 1] += bsum[i >> 8];
    if (i == 0) off[0] = 0;
}

__global__ void k_copyoff(const int* __restrict__ off, int* __restrict__ cur) {
    int i = blockIdx.x * blockDim.x + threadIdx.x;
    if (i < NN) cur[i] = off[i];
}

__global__ void k_scatter(const int* __restrict__ src, const int* __restrict__ dst,
                          int* __restrict__ cur, int2* __restrict__ csr_se) {
    int e = blockIdx.x * blockDim.x + threadIdx.x;
    if (e < NE) {
        int d = dst[e];
        int p = atomicAdd(&cur[d], 1);
        csr_se[p] = make_int2(src[e], e);
    }
}

// ---------------- weight/bias/input prep ----------------
__global__ void k_cvt_x(const float* __restrict__ x, short* __restrict__ xb) {
    int idx = blockIdx.x * 256 + threadIdx.x;
    if (idx >= NN * KP1) return;
    int i = idx / KP1, k = idx - i * KP1;
    xb[idx] = (k < DIN) ? f2bf(x[(size_t)i * DIN + k]) : (short)0;
}

__global__ void k_build_bt1(const float* __restrict__ Wl, const float* __restrict__ Wr,
                            const float* __restrict__ Wres, short* __restrict__ Bt) {
    int idx = blockIdx.x * 256 + threadIdx.x;   // 384*288
    if (idx >= 384 * KP1) return;
    int n = idx / KP1, k = idx - n * KP1;
    float v = 0.f;
    if (k < DIN) {
        const float* W = (n < 128) ? Wl : ((n < 256) ? Wr : Wres);
        v = W[(size_t)k * 128 + (n & 127)];
    }
    Bt[idx] = f2bf(v);
}

__global__ void k_build_bt2(const float* __restrict__ Wl, const float* __restrict__ Wr,
                            short* __restrict__ Bt) {
    int idx = blockIdx.x * 256 + threadIdx.x;   // 256*128
    if (idx >= 256 * 128) return;
    int n = idx >> 7, k = idx & 127;
    const float* W = (n < 128) ? Wl : Wr;
    Bt[idx] = f2bf(W[(size_t)k * 128 + (n & 127)]);
}

__global__ void k_build_bt3(const float* __restrict__ W, short* __restrict__ Bt) {
    int idx = blockIdx.x * 256 + threadIdx.x;   // 128*128
    if (idx >= 128 * 128) return;
    int n = idx >> 7, k = idx & 127;
    Bt[idx] = f2bf(W[(size_t)k * 128 + n]);
}

__global__ void k_cat3(const float* a, const float* b, const float* c, float* o) {
    int t = threadIdx.x;   // 384
    o[t] = (t < 128) ? a[t] : ((t < 256) ? b[t - 128] : c[t - 256]);
}

__global__ void k_cat2(const float* a, const float* b, float* o) {
    int t = threadIdx.x;   // 256
    o[t] = (t < 128) ? a[t] : b[t - 128];
}

// ---------------- bf16 MFMA GEMM: C[M x NS] = A[M x Kpad] @ Bt[NS x Kpad]^T + bias ----------------
template <bool BF16OUT>
__global__ __launch_bounds__(256) void k_mfma_gemm(const short* __restrict__ A,
                                                   const short* __restrict__ Bt,
                                                   const float* __restrict__ bias,
                                                   float* __restrict__ Cf,
                                                   short* __restrict__ Cb,
                                                   int M, int Kpad, int NS) {
    __shared__ short As[128 * 32];
    __shared__ short Bs[128 * 32];
    int t = threadIdx.x;
    int lane = t & 63, wid = t >> 6;
    int wm = (wid & 1) * 64, wn = (wid >> 1) * 64;
    int cl = lane & 15, quad = lane >> 4;
    int row0 = blockIdx.x * 128;
    int col0 = blockIdx.y * 128;

    f32x4 acc[4][4];
#pragma unroll
    for (int i = 0; i < 4; ++i)
#pragma unroll
        for (int j = 0; j < 4; ++j) acc[i][j] = (f32x4)0.f;

    for (int k0 = 0; k0 < Kpad; k0 += 32) {
#pragma unroll
        for (int r = 0; r < 2; ++r) {
            int c = t + r * 256;                     // chunk 0..511
            int m = c >> 2;
            int row = row0 + m; if (row >= M) row = M - 1;
            const char* ga = (const char*)A + ((size_t)row * Kpad + k0) * 2 + (c & 3) * 16;
            gload_lds16(ga, (char*)As + c * 16);
            int n = col0 + m;
            const char* gb = (const char*)Bt + ((size_t)n * Kpad + k0) * 2 + (c & 3) * 16;
            gload_lds16(gb, (char*)Bs + c * 16);
        }
        __syncthreads();

        short8 a[4], b[4];
#pragma unroll
        for (int mi = 0; mi < 4; ++mi)
            a[mi] = *(const short8*)&As[(wm + mi * 16 + cl) * 32 + quad * 8];
#pragma unroll
        for (int ni = 0; ni < 4; ++ni)
            b[ni] = *(const short8*)&Bs[(wn + ni * 16 + cl) * 32 + quad * 8];
#pragma unroll
        for (int mi = 0; mi < 4; ++mi)
#pragma unroll
            for (int ni = 0; ni < 4; ++ni)
                acc[mi][ni] = __builtin_amdgcn_mfma_f32_16x16x32_bf16(a[mi], b[ni], acc[mi][ni], 0, 0, 0);
        __syncthreads();
    }

#pragma unroll
    for (int mi = 0; mi < 4; ++mi)
#pragma unroll
        for (int ni = 0; ni < 4; ++ni) {
            int col = col0 + wn + ni * 16 + cl;
            float bv = bias[col];
#pragma unroll
            for (int r = 0; r < 4; ++r) {
                int row = row0 + wm + mi * 16 + quad * 4 + r;
                if (row < M) {
                    float v = acc[mi][ni][r] + bv;
                    if (BF16OUT) Cb[(size_t)row * NS + col] = f2bf(v);
                    else         Cf[(size_t)row * NS + col] = v;
                }
            }
        }
}

// ---------------- block helpers ----------------
__device__ __forceinline__ float block_sum128(float v, volatile float* red) {
#pragma unroll
    for (int o = 32; o > 0; o >>= 1) v += __shfl_down(v, o, 64);
    int w = threadIdx.x >> 6;
    __syncthreads();
    if ((threadIdx.x & 63) == 0) red[w] = v;
    __syncthreads();
    return red[0] + red[1];
}

// ---------------- fused edge-score + online-softmax aggregate + epilogue ----------------
// One block (128 thr) per dst node i. Thread t owns feature t (h=t>>5, c=t&31).
// Per in-edge: ee_t = ea[e]·We[:,t]; m_t = xl[s][t]+xr[i][t]+ee_t; p = leaky(m)·att_t;
// s_h = reduce_32(p); online softmax over edges; acc_t += alpha·xl[s][t].
// Epilogue: +bias, ELU, +residual, LayerNorm, store bf16.
__global__ __launch_bounds__(128) void k_fused_agg(const int* __restrict__ off,
                                                   const int2* __restrict__ csr_se,
                                                   const short* __restrict__ C, int stride,
                                                   const float* __restrict__ ea,
                                                   const float* __restrict__ We,
                                                   const float* __restrict__ att,
                                                   const short* __restrict__ resid, int rstride,
                                                   const float* __restrict__ bias,
                                                   const float* __restrict__ gamma,
                                                   const float* __restrict__ beta,
                                                   short* __restrict__ outb) {
    __shared__ float red[2];
    int i = blockIdx.x;
    int t = threadIdx.x;
    int b0 = off[i], b1 = off[i + 1];

    float wreg[EDIM];
#pragma unroll
    for (int k = 0; k < EDIM; ++k) wreg[k] = We[k * 128 + t];
    float att_t = att[t];
    float xr_t = bf2f(C[(size_t)i * stride + 128 + t]);

    float m_run = -INFINITY, l_run = 0.f, acc = 0.f;

    for (int pos = b0; pos < b1; ++pos) {
        int2 se = csr_se[pos];
        int s = se.x, e = se.y;
        const float4* ea4 = reinterpret_cast<const float4*>(&ea[(size_t)e * EDIM]);
        float ee = 0.f;
#pragma unroll
        for (int j = 0; j < 4; ++j) {
            float4 v = ea4[j];
            ee += v.x * wreg[j * 4 + 0] + v.y * wreg[j * 4 + 1]
                + v.z * wreg[j * 4 + 2] + v.w * wreg[j * 4 + 3];
        }
        float xlv = bf2f(C[(size_t)s * stride + t]);
        float m = xlv + xr_t + ee;
        float g = m > 0.f ? m : 0.2f * m;
        float p = g * att_t;
#pragma unroll
        for (int o = 16; o > 0; o >>= 1) p += __shfl_xor(p, o, 64);  // within 32-lane head group
        float snew = p;
        float mn = fmaxf(m_run, snew);
        float sc = __expf(m_run - mn);
        float pe = __expf(snew - mn);
        l_run = l_run * sc + pe;
        acc = acc * sc + pe * xlv;
        m_run = mn;
    }

    float o = acc / (l_run + 1e-16f) + bias[t];
    o = o > 0.f ? o : (__expf(o) - 1.f);                 // ELU
    float v = o + bf2f(resid[(size_t)i * rstride + t]);  // + residual
    float mean = block_sum128(v, red) * (1.f / 128.f);
    float d = v - mean;
    float var = block_sum128(d * d, red) * (1.f / 128.f);
    float r = d * rsqrtf(var + 1e-5f) * gamma[t] + beta[t];
    outb[(size_t)i * 128 + t] = f2bf(r);
}

// ---------------- plain LN over 128 ----------------
__global__ __launch_bounds__(128) void k_ln(const float* __restrict__ in,
                                            const float* __restrict__ gamma,
                                            const float* __restrict__ beta,
                                            float* __restrict__ out) {
    __shared__ float red[2];
    int i = blockIdx.x, t = threadIdx.x;
    float v = in[(size_t)i * 128 + t];
    float mean = block_sum128(v, red) * (1.f / 128.f);
    float d = v - mean;
    float var = block_sum128(d * d, red) * (1.f / 128.f);
    out[(size_t)i * 128 + t] = d * rsqrtf(var + 1e-5f) * gamma[t] + beta[t];
}

extern "C" void kernel_launch(void* const* d_in, const int* in_sizes, int n_in,
                              void* d_out, int out_size, void* d_ws, size_t ws_size,
                              hipStream_t stream) {
    (void)in_sizes; (void)n_in; (void)out_size; (void)ws_size;
    const float* x     = (const float*)d_in[0];
    const float* ea    = (const float*)d_in[1];
    const float* Wl1   = (const float*)d_in[2];
    const float* bl1   = (const float*)d_in[3];
    const float* Wr1   = (const float*)d_in[4];
    const float* br1   = (const float*)d_in[5];
    const float* We1   = (const float*)d_in[6];
    const float* att1  = (const float*)d_in[7];
    const float* bias1 = (const float*)d_in[8];
    const float* Wl2   = (const float*)d_in[9];
    const float* bl2   = (const float*)d_in[10];
    const float* Wr2   = (const float*)d_in[11];
    const float* br2   = (const float*)d_in[12];
    const float* We2   = (const float*)d_in[13];
    const float* att2  = (const float*)d_in[14];
    const float* bias2 = (const float*)d_in[15];
    const float* Wres  = (const float*)d_in[16];
    const float* bres  = (const float*)d_in[17];
    const float* Wout  = (const float*)d_in[18];
    const float* bout  = (const float*)d_in[19];
    const float* g1    = (const float*)d_in[20];
    const float* bn1   = (const float*)d_in[21];
    const float* g2    = (const float*)d_in[22];
    const float* bn2   = (const float*)d_in[23];
    const float* go    = (const float*)d_in[24];
    const float* bo    = (const float*)d_in[25];
    const int*   ei    = (const int*)d_in[26];
    const int* srcv = ei;
    const int* dstv = ei + NE;
    float* outp = (float*)d_out;

    char* p = (char*)d_ws;
    auto carve = [&](size_t bytes) {
        char* r = p;
        p += (bytes + 255) & ~(size_t)255;
        return r;
    };
    short* xb    = (short*)carve((size_t)NN * KP1 * 2);
    short* Wt1   = (short*)carve((size_t)384 * KP1 * 2);
    short* Wt2   = (short*)carve((size_t)256 * 128 * 2);
    short* Wt3   = (short*)carve((size_t)128 * 128 * 2);
    float* bcat1 = (float*)carve(384 * 4);
    float* bcat2 = (float*)carve(256 * 4);
    short* C1    = (short*)carve((size_t)NN * 384 * 2);   // bf16 [xl|xr|res]
    short* h1b   = (short*)carve((size_t)NN * 128 * 2);
    short* h2b   = (short*)carve((size_t)NN * 128 * 2);
    float* C3    = (float*)carve((size_t)NN * 128 * 4);
    int* off     = (int*)carve((size_t)(NN + 1) * 4);
    int* cur     = (int*)carve((size_t)NN * 4);
    int* bsum    = (int*)carve(256 * 4);
    int2* csr_se = (int2*)carve((size_t)NE * 8);

    short* C2 = C1;                                  // stride 256, reuse after layer 1

    const int NB = (NN + 255) / 256;                 // 196

    // ---- CSR build ----
    hipMemsetAsync(cur, 0, (size_t)NN * 4, stream);
    k_count<<<(NE + 255) / 256, 256, 0, stream>>>(dstv, cur);
    k_scan1<<<NB, 256, 0, stream>>>(cur, off, bsum);
    k_scan2<<<1, 256, 0, stream>>>(bsum, NB);
    k_scan3<<<NB, 256, 0, stream>>>(off, bsum);
    k_copyoff<<<NB, 256, 0, stream>>>(off, cur);
    k_scatter<<<(NE + 255) / 256, 256, 0, stream>>>(srcv, dstv, cur, csr_se);

    // ---- prep ----
    k_cvt_x<<<((size_t)NN * KP1 + 255) / 256, 256, 0, stream>>>(x, xb);
    k_build_bt1<<<(384 * KP1 + 255) / 256, 256, 0, stream>>>(Wl1, Wr1, Wres, Wt1);
    k_build_bt2<<<(256 * 128 + 255) / 256, 256, 0, stream>>>(Wl2, Wr2, Wt2);
    k_build_bt3<<<(128 * 128 + 255) / 256, 256, 0, stream>>>(Wout, Wt3);
    k_cat3<<<1, 384, 0, stream>>>(bl1, br1, bres, bcat1);
    k_cat2<<<1, 256, 0, stream>>>(bl2, br2, bcat2);

    int mb = (NN + 127) / 128;                       // 391

    // ---- layer 1 ----
    k_mfma_gemm<true><<<dim3(mb, 3), 256, 0, stream>>>(xb, Wt1, bcat1, nullptr, C1, NN, KP1, 384);
    k_fused_agg<<<NN, 128, 0, stream>>>(off, csr_se, C1, 384, ea, We1, att1,
                                        C1 + 256, 384, bias1, g1, bn1, h1b);
    // ---- layer 2 ----
    k_mfma_gemm<true><<<dim3(mb, 2), 256, 0, stream>>>(h1b, Wt2, bcat2, nullptr, C2, NN, 128, 256);
    k_fused_agg<<<NN, 128, 0, stream>>>(off, csr_se, C2, 256, ea, We2, att2,
                                        h1b, 128, bias2, g2, bn2, h2b);
    // ---- output ----
    k_mfma_gemm<false><<<dim3(mb, 1), 256, 0, stream>>>(h2b, Wt3, bout, C3, nullptr, NN, 128, 128);
    k_ln<<<NN, 128, 0, stream>>>(C3, go, bo, outp);
}